// Round 1
// baseline (585.117 us; speedup 1.0000x reference)
//
#include <hip/hip_runtime.h>
#include <stdint.h>

#define K_DIM 512
#define N_OUT 512
#define BM 128
#define BN 128
#define BK 32
#define LDS_STRIDE 40  // 32 + 8 pad bf16 elems -> 80 B row stride, breaks pow2 bank aliasing

typedef __bf16 bf16x8 __attribute__((ext_vector_type(8)));
typedef float f32x4 __attribute__((ext_vector_type(4)));

__device__ inline unsigned short f2bf(float f) {
  // round-to-nearest-even float -> bf16 (inputs are finite; no NaN handling needed)
  unsigned u = __float_as_uint(f);
  u += 0x7fffu + ((u >> 16) & 1u);
  return (unsigned short)(u >> 16);
}

__global__ __launch_bounds__(256) void gemm_bias_relu_kernel(
    const float* __restrict__ x, const float* __restrict__ W,
    const float* __restrict__ b, float* __restrict__ out, int M) {
  __shared__ __align__(16) unsigned short Als[BM * LDS_STRIDE];
  __shared__ __align__(16) unsigned short Bls[BN * LDS_STRIDE];

  const int tid = threadIdx.x;
  const int lane = tid & 63;
  const int quad = lane >> 4;   // lane>>4 : which 16-lane group
  const int l16 = lane & 15;
  const int waveId = tid >> 6;
  const int wm = (waveId >> 1) * 64;  // wave's M offset within 128-tile
  const int wn = (waveId & 1) * 64;   // wave's N offset within 128-tile

  const int blockM = blockIdx.y * BM;
  const int blockN = blockIdx.x * BN;

  f32x4 acc[4][4] = {};  // 4x4 MFMA tiles of 16x16, fp32 accum

  for (int k0 = 0; k0 < K_DIM; k0 += BK) {
    // ---- stage A (x tile) and B (W tile) into LDS as bf16 ----
    // 128 rows x 32 cols = 1024 float4 chunks each; 256 threads x 4 chunks
#pragma unroll
    for (int i = 0; i < 4; ++i) {
      int idx = i * 256 + tid;   // consecutive across threads -> coalesced 16B/lane
      int row = idx >> 3;        // 0..127
      int c4 = idx & 7;          // float4 index within 32-col row

      float4 va = make_float4(0.f, 0.f, 0.f, 0.f);
      int grow = blockM + row;
      if (grow < M)
        va = *(const float4*)(x + (size_t)grow * K_DIM + k0 + c4 * 4);
      ushort4 ha;
      ha.x = f2bf(va.x); ha.y = f2bf(va.y); ha.z = f2bf(va.z); ha.w = f2bf(va.w);
      *(ushort4*)(&Als[row * LDS_STRIDE + c4 * 4]) = ha;

      float4 vb = *(const float4*)(W + (size_t)(blockN + row) * K_DIM + k0 + c4 * 4);
      ushort4 hb;
      hb.x = f2bf(vb.x); hb.y = f2bf(vb.y); hb.z = f2bf(vb.z); hb.w = f2bf(vb.w);
      *(ushort4*)(&Bls[row * LDS_STRIDE + c4 * 4]) = hb;
    }
    __syncthreads();

    // ---- LDS -> fragments (b128 reads, 16B aligned: 80B row stride, 16B quad offset)
    bf16x8 af[4], bfr[4];
#pragma unroll
    for (int mi = 0; mi < 4; ++mi)
      af[mi] = *(const bf16x8*)(&Als[(wm + mi * 16 + l16) * LDS_STRIDE + quad * 8]);
#pragma unroll
    for (int ni = 0; ni < 4; ++ni)
      bfr[ni] = *(const bf16x8*)(&Bls[(wn + ni * 16 + l16) * LDS_STRIDE + quad * 8]);

#pragma unroll
    for (int mi = 0; mi < 4; ++mi)
#pragma unroll
      for (int ni = 0; ni < 4; ++ni)
        acc[mi][ni] = __builtin_amdgcn_mfma_f32_16x16x32_bf16(af[mi], bfr[ni], acc[mi][ni], 0, 0, 0);
    __syncthreads();
  }

  // ---- epilogue: bias + relu, C/D layout col=lane&15, row=quad*4+reg ----
#pragma unroll
  for (int ni = 0; ni < 4; ++ni) {
    int gcol = blockN + wn + ni * 16 + l16;
    float bias = b[gcol];
#pragma unroll
    for (int mi = 0; mi < 4; ++mi) {
#pragma unroll
      for (int r = 0; r < 4; ++r) {
        int grow = blockM + wm + mi * 16 + quad * 4 + r;
        if (grow < M) {
          float v = acc[mi][ni][r] + bias;
          out[(size_t)grow * N_OUT + gcol] = v > 0.f ? v : 0.f;
        }
      }
    }
  }
}

// out[col[e], 0] += x[e, 0]
__global__ void scatter_kernel(const float* __restrict__ x,
                               const int* __restrict__ ei,
                               float* __restrict__ out, int E) {
  int e = blockIdx.x * 256 + threadIdx.x;
  if (e < E) {
    int c = ei[E + e];  // edge_index row 1
    atomicAdd(out + (size_t)c * N_OUT, x[(size_t)e * K_DIM]);
  }
}

extern "C" void kernel_launch(void* const* d_in, const int* in_sizes, int n_in,
                              void* d_out, int out_size, void* d_ws, size_t ws_size,
                              hipStream_t stream) {
  const float* x = (const float*)d_in[0];
  const int* ei = (const int*)d_in[1];
  const float* W = (const float*)d_in[2];
  const float* b = (const float*)d_in[3];
  float* out = (float*)d_out;

  int M = in_sizes[0] / K_DIM;   // 100000
  int E = in_sizes[1] / 2;       // 100000

  dim3 grid(N_OUT / BN, (M + BM - 1) / BM);  // (4, 782)
  gemm_bias_relu_kernel<<<grid, 256, 0, stream>>>(x, W, b, out, M);
  scatter_kernel<<<(E + 255) / 256, 256, 0, stream>>>(x, ei, out, E);
}

// Round 2
// 500.863 us; speedup vs baseline: 1.1682x; 1.1682x over previous
//
#include <hip/hip_runtime.h>
#include <stdint.h>

#define K_DIM 512
#define N_OUT 512
#define BM 128
#define BN 128
#define BK 64

typedef __bf16 bf16x8 __attribute__((ext_vector_type(8)));
typedef float f32x4 __attribute__((ext_vector_type(4)));
typedef unsigned short ushort8 __attribute__((ext_vector_type(8)));

__device__ inline unsigned short f2bf(float f) {
  unsigned u = __float_as_uint(f);
  u += 0x7fffu + ((u >> 16) & 1u);
  return (unsigned short)(u >> 16);
}

// ---------------- phase 1: fp32 -> bf16 conversion into workspace ----------------
__global__ __launch_bounds__(256) void cvt_bf16_kernel(const float* __restrict__ src,
                                                       unsigned short* __restrict__ dst,
                                                       int n8) {
  int i = blockIdx.x * 256 + threadIdx.x;
  if (i >= n8) return;
  const float4* s = (const float4*)src + (size_t)i * 2;
  float4 a = s[0], c = s[1];
  ushort8 o;
  o[0] = f2bf(a.x); o[1] = f2bf(a.y); o[2] = f2bf(a.z); o[3] = f2bf(a.w);
  o[4] = f2bf(c.x); o[5] = f2bf(c.y); o[6] = f2bf(c.z); o[7] = f2bf(c.w);
  *(ushort8*)(dst + (size_t)i * 8) = o;
}

// ---------------- phase 2: bf16 GEMM, m97 structure (global_load_lds w=16) -------
__global__ __launch_bounds__(256) void gemm_bf16_kernel(
    const unsigned short* __restrict__ xb, const unsigned short* __restrict__ wb,
    const float* __restrict__ b, float* __restrict__ out, int M) {
  __shared__ __align__(16) unsigned short Als[BM * BK];  // 16 KB, unpadded (global_load_lds)
  __shared__ __align__(16) unsigned short Bls[BN * BK];  // 16 KB

  const int tid = threadIdx.x;
  const int lane = tid & 63;
  const int quad = lane >> 4;
  const int l16 = lane & 15;
  const int waveId = tid >> 6;
  const int wm = (waveId >> 1) * 64;
  const int wn = (waveId & 1) * 64;
  const int blockM = blockIdx.y * BM;
  const int blockN = blockIdx.x * BN;

  // staging assignment: thread handles LDS 16B-chunk ch = i*256+tid (lane-contiguous
  // per wave, as global_load_lds requires); global source chunk is XOR-swizzled so
  // fragment ds_read_b128 spreads across all 32 banks (2-way = free).
  size_t goffA[4], goffB[4];
  int ldsoff[4];
#pragma unroll
  for (int i = 0; i < 4; ++i) {
    int ch = i * 256 + tid;
    int row = ch >> 3;       // 0..127
    int c8 = ch & 7;         // 16B chunk within 128B row
    int sc = c8 ^ (row & 7); // swizzled global chunk
    int ga_row = blockM + row;
    if (ga_row > M - 1) ga_row = M - 1;  // clamp tail (results masked in epilogue)
    goffA[i] = (size_t)ga_row * K_DIM + sc * 8;
    goffB[i] = (size_t)(blockN + row) * K_DIM + sc * 8;
    ldsoff[i] = ch * 8;  // elements; *2B = ch*16 bytes
  }

  f32x4 acc[4][4] = {};

  for (int k0 = 0; k0 < K_DIM; k0 += BK) {
#pragma unroll
    for (int i = 0; i < 4; ++i) {
      __builtin_amdgcn_global_load_lds(
          (const __attribute__((address_space(1))) void*)(xb + goffA[i] + k0),
          (__attribute__((address_space(3))) void*)(&Als[ldsoff[i]]), 16, 0, 0);
      __builtin_amdgcn_global_load_lds(
          (const __attribute__((address_space(1))) void*)(wb + goffB[i] + k0),
          (__attribute__((address_space(3))) void*)(&Bls[ldsoff[i]]), 16, 0, 0);
    }
    __syncthreads();

#pragma unroll
    for (int s = 0; s < 2; ++s) {  // two K=32 steps within BK=64
      bf16x8 af[4], bfr[4];
#pragma unroll
      for (int mi = 0; mi < 4; ++mi) {
        int r = wm + mi * 16 + l16;
        int c = (s * 4 + quad) ^ (r & 7);
        af[mi] = *(const bf16x8*)(&Als[r * BK + c * 8]);
      }
#pragma unroll
      for (int ni = 0; ni < 4; ++ni) {
        int r = wn + ni * 16 + l16;
        int c = (s * 4 + quad) ^ (r & 7);
        bfr[ni] = *(const bf16x8*)(&Bls[r * BK + c * 8]);
      }
#pragma unroll
      for (int mi = 0; mi < 4; ++mi)
#pragma unroll
        for (int ni = 0; ni < 4; ++ni)
          acc[mi][ni] = __builtin_amdgcn_mfma_f32_16x16x32_bf16(af[mi], bfr[ni], acc[mi][ni], 0, 0, 0);
    }
    __syncthreads();
  }

  // epilogue: bias + relu; C/D layout col=lane&15, row=quad*4+reg (m89/m91)
#pragma unroll
  for (int ni = 0; ni < 4; ++ni) {
    int gcol = blockN + wn + ni * 16 + l16;
    float bias = b[gcol];
#pragma unroll
    for (int mi = 0; mi < 4; ++mi) {
#pragma unroll
      for (int r = 0; r < 4; ++r) {
        int grow = blockM + wm + mi * 16 + quad * 4 + r;
        if (grow < M) {
          float v = acc[mi][ni][r] + bias;
          out[(size_t)grow * N_OUT + gcol] = v > 0.f ? v : 0.f;
        }
      }
    }
  }
}

// ---------------- fallback: round-1 fused-conversion GEMM (if ws too small) ------
#define LDS_STRIDE 40
__global__ __launch_bounds__(256) void gemm_fused_kernel(
    const float* __restrict__ x, const float* __restrict__ W,
    const float* __restrict__ b, float* __restrict__ out, int M) {
  __shared__ __align__(16) unsigned short Als[BM * LDS_STRIDE];
  __shared__ __align__(16) unsigned short Bls[BN * LDS_STRIDE];
  const int tid = threadIdx.x;
  const int lane = tid & 63;
  const int quad = lane >> 4;
  const int l16 = lane & 15;
  const int waveId = tid >> 6;
  const int wm = (waveId >> 1) * 64;
  const int wn = (waveId & 1) * 64;
  const int blockM = blockIdx.y * BM;
  const int blockN = blockIdx.x * BN;
  f32x4 acc[4][4] = {};
  for (int k0 = 0; k0 < K_DIM; k0 += 32) {
#pragma unroll
    for (int i = 0; i < 4; ++i) {
      int idx = i * 256 + tid;
      int row = idx >> 3;
      int c4 = idx & 7;
      float4 va = make_float4(0.f, 0.f, 0.f, 0.f);
      int grow = blockM + row;
      if (grow < M) va = *(const float4*)(x + (size_t)grow * K_DIM + k0 + c4 * 4);
      ushort4 ha;
      ha.x = f2bf(va.x); ha.y = f2bf(va.y); ha.z = f2bf(va.z); ha.w = f2bf(va.w);
      *(ushort4*)(&Als[row * LDS_STRIDE + c4 * 4]) = ha;
      float4 vb = *(const float4*)(W + (size_t)(blockN + row) * K_DIM + k0 + c4 * 4);
      ushort4 hb;
      hb.x = f2bf(vb.x); hb.y = f2bf(vb.y); hb.z = f2bf(vb.z); hb.w = f2bf(vb.w);
      *(ushort4*)(&Bls[row * LDS_STRIDE + c4 * 4]) = hb;
    }
    __syncthreads();
    bf16x8 af[4], bfr[4];
#pragma unroll
    for (int mi = 0; mi < 4; ++mi)
      af[mi] = *(const bf16x8*)(&Als[(wm + mi * 16 + l16) * LDS_STRIDE + quad * 8]);
#pragma unroll
    for (int ni = 0; ni < 4; ++ni)
      bfr[ni] = *(const bf16x8*)(&Bls[(wn + ni * 16 + l16) * LDS_STRIDE + quad * 8]);
#pragma unroll
    for (int mi = 0; mi < 4; ++mi)
#pragma unroll
      for (int ni = 0; ni < 4; ++ni)
        acc[mi][ni] = __builtin_amdgcn_mfma_f32_16x16x32_bf16(af[mi], bfr[ni], acc[mi][ni], 0, 0, 0);
    __syncthreads();
  }
#pragma unroll
  for (int ni = 0; ni < 4; ++ni) {
    int gcol = blockN + wn + ni * 16 + l16;
    float bias = b[gcol];
#pragma unroll
    for (int mi = 0; mi < 4; ++mi) {
#pragma unroll
      for (int r = 0; r < 4; ++r) {
        int grow = blockM + wm + mi * 16 + quad * 4 + r;
        if (grow < M) {
          float v = acc[mi][ni][r] + bias;
          out[(size_t)grow * N_OUT + gcol] = v > 0.f ? v : 0.f;
        }
      }
    }
  }
}

// out[col[e], 0] += x[e, 0]
__global__ void scatter_kernel(const float* __restrict__ x,
                               const int* __restrict__ ei,
                               float* __restrict__ out, int E) {
  int e = blockIdx.x * 256 + threadIdx.x;
  if (e < E) {
    int c = ei[E + e];
    atomicAdd(out + (size_t)c * N_OUT, x[(size_t)e * K_DIM]);
  }
}

extern "C" void kernel_launch(void* const* d_in, const int* in_sizes, int n_in,
                              void* d_out, int out_size, void* d_ws, size_t ws_size,
                              hipStream_t stream) {
  const float* x = (const float*)d_in[0];
  const int* ei = (const int*)d_in[1];
  const float* W = (const float*)d_in[2];
  const float* b = (const float*)d_in[3];
  float* out = (float*)d_out;

  int M = in_sizes[0] / K_DIM;  // 100000
  int E = in_sizes[1] / 2;      // 100000

  size_t x_elems = (size_t)M * K_DIM;           // 51,200,000
  size_t w_elems = (size_t)N_OUT * K_DIM;       // 262,144
  size_t need = (x_elems + w_elems) * 2;        // bf16 bytes: 102,924,288

  dim3 grid(N_OUT / BN, (M + BM - 1) / BM);  // (4, 782)

  if (ws_size >= need) {
    unsigned short* xb = (unsigned short*)d_ws;
    unsigned short* wb = xb + x_elems;
    int n8x = (int)(x_elems / 8);  // 6,400,000
    int n8w = (int)(w_elems / 8);  // 32,768
    cvt_bf16_kernel<<<(n8x + 255) / 256, 256, 0, stream>>>(x, xb, n8x);
    cvt_bf16_kernel<<<(n8w + 255) / 256, 256, 0, stream>>>(W, wb, n8w);
    gemm_bf16_kernel<<<grid, 256, 0, stream>>>(xb, wb, b, out, M);
  } else {
    gemm_fused_kernel<<<grid, 256, 0, stream>>>(x, W, b, out, M);
  }
  scatter_kernel<<<(E + 255) / 256, 256, 0, stream>>>(x, ei, out, E);
}